// Round 1
// baseline (47397.302 us; speedup 1.0000x reference)
//
#include <hip/hip_runtime.h>
#include <math.h>

// LSTM: B=64, T=1024, I=256, H=512, gates order (i,j,f,o), forget bias 1.0.
// Persistent-kernel design:
//   grid = 256 WGs = 8 batch-groups (8 batches each) x 32 hidden-groups
//   (16 h-indices -> 64 gate columns each). 512 threads/WG, 1 WG/CU
//   (enforced by >80KB LDS). W slice [768x64] lives in registers
//   (96 VGPR/lane, no replication). Per step: stage x_t + h_t into LDS,
//   FMA with register W (split-K across lanes), butterfly-reduce, gate
//   nonlinearities by 128 updater threads holding c in registers, h
//   published to a double-buffered global buffer, per-batch-group
//   release/acquire barrier (32 WGs) before the next step.

#define BB   64
#define TT   1024
#define II   256
#define HH   512
#define KD   768      // I + H
#define GG   2048     // 4H
#define NBG  8        // batch groups
#define NHG  32       // hidden groups per batch group
#define BPG  8        // batches per group
#define NWG  256
#define NTHR 512
#define PAD_LDS_BYTES 57344   // dynamic LDS pad -> ~84KB total -> 1 WG/CU

__device__ __forceinline__ float fsig(float v) {
  return 1.0f / (1.0f + __expf(-v));        // graceful at extremes
}
__device__ __forceinline__ float ftanh(float v) {
  const float a = fabsf(v);
  const float e = __expf(2.0f * a);         // overflow -> inf -> r = 1
  const float r = 1.0f - 2.0f / (e + 1.0f);
  return v < 0.0f ? -r : r;
}

__global__ void zero_bar_kernel(unsigned int* bar) {
  if (threadIdx.x < NBG) bar[threadIdx.x] = 0u;
}

__global__ void __launch_bounds__(NTHR, 2) lstm_persistent(
    const float* __restrict__ x, const float* __restrict__ W,
    const float* __restrict__ bias, float* __restrict__ out,
    float* __restrict__ hbuf, unsigned int* bar)
{
  __shared__ float xh[BPG][KD];      // 24 KB: [x_t | h_t] rows for 8 batches
  __shared__ float gates[BPG][64];   // 2 KB: this WG's gate pre-activations
  extern __shared__ float lds_pad[]; // occupancy limiter (unused)
  (void)lds_pad;

  const int tid  = threadIdx.x;
  const int wave = tid >> 6;
  const int lane = tid & 63;
  const int cg   = lane & 1;         // column sub-group within wave
  const int kc   = lane >> 1;        // 32 K-chunks per wave
  const int bg   = blockIdx.x / NHG; // batch group 0..7
  const int hg   = blockIdx.x % NHG; // hidden group 0..31

  // ---- W slice -> registers. Lane owns 4 consecutive local cols and the
  // interleaved k-set {kc*4 + 128*j + kk : j<6, kk<4} (bank-spread reads).
  // local col c in [0,64): global col = (c>>4)*512 + hg*16 + (c&15).
  float Wr[6][4][4];                 // [j][kk][cj]
  const int clb  = wave * 8 + cg * 4;
  const int col0 = (clb >> 4) * HH + hg * 16 + (clb & 15);
  #pragma unroll
  for (int j = 0; j < 6; ++j)
    #pragma unroll
    for (int kk = 0; kk < 4; ++kk) {
      const int k = kc * 4 + 128 * j + kk;
      const float4 wv = *(const float4*)&W[(size_t)k * GG + col0];
      Wr[j][kk][0] = wv.x; Wr[j][kk][1] = wv.y;
      Wr[j][kk][2] = wv.z; Wr[j][kk][3] = wv.w;
    }

  // After the halving butterfly, this lane holds the full sum for flat
  // accumulator index afin (bit-reversed kc), i.e. output (wb, wcl).
  const int afin = (((lane >> 1) & 1) << 4) | (((lane >> 2) & 1) << 3) |
                   (((lane >> 3) & 1) << 2) | (((lane >> 4) & 1) << 1) |
                   ((lane >> 5) & 1);
  const int wb   = afin >> 2;
  const int wcl  = clb + (afin & 3);
  const float wbias = bias[(wcl >> 4) * HH + hg * 16 + (wcl & 15)];

  float c_state = 0.0f;              // persistent cell state (tid < 128)

  for (int t = 0; t < TT; ++t) {
    // ---- stage x_t (8 rows x 256) : one b128 per thread, coalesced
    {
      const int bl = tid >> 6, kb4 = (tid & 63) * 4;
      *(float4*)&xh[bl][kb4] =
          *(const float4*)&x[((size_t)(bg * BPG + bl) * TT + t) * II + kb4];
    }
    // ---- stage h_t (8 rows x 512) from double buffer (zeros at t=0)
    if (t == 0) {
      #pragma unroll
      for (int r = 0; r < 2; ++r) {
        const int idx = r * NTHR + tid;
        const int bl = idx >> 7, kb4 = (idx & 127) * 4;
        *(float4*)&xh[bl][II + kb4] = float4{0.f, 0.f, 0.f, 0.f};
      }
    } else {
      const float* hb = hbuf + (size_t)(t & 1) * BB * HH;
      #pragma unroll
      for (int r = 0; r < 2; ++r) {
        const int idx = r * NTHR + tid;
        const int bl = idx >> 7, kb4 = (idx & 127) * 4;
        *(float4*)&xh[bl][II + kb4] =
            *(const float4*)&hb[(size_t)(bg * BPG + bl) * HH + kb4];
      }
    }
    __syncthreads();

    // ---- GEMM fragment: 8 batches x 4 cols x 24 k per lane
    float acc[32];
    #pragma unroll
    for (int i = 0; i < 32; ++i) acc[i] = 0.0f;

    #pragma unroll
    for (int j = 0; j < 6; ++j) {
      const int kb = kc * 4 + 128 * j;
      #pragma unroll
      for (int bl = 0; bl < 8; ++bl) {
        const float4 xv = *(const float4*)&xh[bl][kb];
        #pragma unroll
        for (int cj = 0; cj < 4; ++cj) {
          float a = acc[bl * 4 + cj];
          a = fmaf(xv.x, Wr[j][0][cj], a);
          a = fmaf(xv.y, Wr[j][1][cj], a);
          a = fmaf(xv.z, Wr[j][2][cj], a);
          a = fmaf(xv.w, Wr[j][3][cj], a);
          acc[bl * 4 + cj] = a;
        }
      }
    }

    // ---- halving butterfly over the 32 kc-lanes (masks 2..32)
    #pragma unroll
    for (int s = 0; s < 5; ++s) {
      const int m   = 2 << s;
      const int cnt = 16 >> s;
      const bool hi = (lane & m) != 0;
      #pragma unroll
      for (int i = 0; i < cnt; ++i) {
        const float send  = hi ? acc[i] : acc[i + cnt];
        const float other = __shfl_xor(send, m, 64);
        acc[i] = (hi ? acc[i + cnt] : acc[i]) + other;
      }
    }
    gates[wb][wcl] = acc[0] + wbias;
    __syncthreads();

    // ---- elementwise LSTM update: 128 threads own (batch, h) pairs
    if (tid < 128) {
      const int ubt = tid >> 4, uh = tid & 15;
      const float gi = gates[ubt][uh];
      const float gj = gates[ubt][16 + uh];
      const float gf = gates[ubt][32 + uh];
      const float go = gates[ubt][48 + uh];
      c_state = fsig(gf + 1.0f) * c_state + fsig(gi) * ftanh(gj);
      const float hn = fsig(go) * ftanh(c_state);
      const int gb = bg * BPG + ubt;
      const int gh = hg * 16 + uh;
      out[((size_t)gb * TT + t) * HH + gh] = hn;
      hbuf[(size_t)((t + 1) & 1) * BB * HH + (size_t)gb * HH + gh] = hn;
    }
    __threadfence();     // make h stores device-visible before arrival
    __syncthreads();

    // ---- batch-group barrier: 32 WGs, monotonic counter
    if (tid == 0) {
      __hip_atomic_fetch_add(&bar[bg], 1u, __ATOMIC_RELEASE,
                             __HIP_MEMORY_SCOPE_AGENT);
      const unsigned tgt = (unsigned)(t + 1) * NHG;
      while (__hip_atomic_load(&bar[bg], __ATOMIC_ACQUIRE,
                               __HIP_MEMORY_SCOPE_AGENT) < tgt) { }
    }
    __syncthreads();
  }
}

extern "C" void kernel_launch(void* const* d_in, const int* in_sizes, int n_in,
                              void* d_out, int out_size, void* d_ws, size_t ws_size,
                              hipStream_t stream) {
  const float* x    = (const float*)d_in[0];   // [64,1024,256]
  const float* W    = (const float*)d_in[1];   // [768,2048]
  const float* bias = (const float*)d_in[2];   // [2048]
  float* out = (float*)d_out;                  // [64,1024,512]

  unsigned int* bar = (unsigned int*)d_ws;           // 8 counters
  float* hbuf = (float*)((char*)d_ws + 256);         // 2 x [64,512] f32

  zero_bar_kernel<<<1, 64, 0, stream>>>(bar);
  lstm_persistent<<<NWG, NTHR, PAD_LDS_BYTES, stream>>>(x, W, bias, out,
                                                        hbuf, bar);
}

// Round 4
// 14254.938 us; speedup vs baseline: 3.3250x; 3.3250x over previous
//
#include <hip/hip_runtime.h>
#include <math.h>

// LSTM: B=64, T=1024, I=256, H=512, gates (i,j,f,o), forget bias 1.0.
// Persistent kernel: 256 WGs = 8 batch-groups x 32 hidden-groups, 1 WG/CU
// (LDS pad). Per WG: W slice [768x64] in VGPRs (volatile-asm loads so the
// compiler cannot rematerialize; round-1 VGPR=88 proved it re-read W every
// step). Cross-WG h exchange + barrier use EXPLICIT sc0 sc1 (system-scope,
// cache-bypassing) loads/stores in inline asm -> always served by the
// coherence point, no buffer_inv/buffer_wbl2 ever (round-1 killer), no
// stale-L2 spin deadlock (round-2 risk). Barrier arrivals are relaxed
// atomic RMWs (execute at the coherence point by definition).

#define BB   64
#define TT   1024
#define II   256
#define HH   512
#define KD   768      // I + H
#define GG   2048     // 4H
#define NBG  8        // batch groups
#define NHG  32       // hidden groups per batch group
#define BPG  8        // batches per group
#define NWG  256
#define NTHR 512
#define PAD_LDS_BYTES 57344   // dynamic LDS pad -> ~84KB total -> 1 WG/CU

__device__ __forceinline__ float fsig(float v) {
  return 1.0f / (1.0f + __expf(-v));
}
__device__ __forceinline__ float ftanh(float v) {
  const float a = fabsf(v);
  const float e = __expf(2.0f * a);         // overflow -> inf -> r = 1
  const float r = 1.0f - 2.0f / (e + 1.0f);
  return v < 0.0f ? -r : r;
}

__global__ void zero_bar_kernel(unsigned int* bar) {
  if (threadIdx.x < NBG)
    __hip_atomic_store(&bar[threadIdx.x], 0u, __ATOMIC_RELAXED,
                       __HIP_MEMORY_SCOPE_SYSTEM);   // write-through
}

__global__ void __launch_bounds__(NTHR, 2) lstm_persistent(
    const float* __restrict__ x, const float* __restrict__ W,
    const float* __restrict__ bias, float* __restrict__ out,
    float* __restrict__ hbuf, unsigned int* bar)
{
  __shared__ float xh[BPG][KD];      // 24 KB: [x_t | h_t] rows, 8 batches
  __shared__ float gates[BPG][64];   // 2 KB
  extern __shared__ float lds_pad[]; // occupancy limiter (unused)
  (void)lds_pad;

  const int tid  = threadIdx.x;
  const int wave = tid >> 6;
  const int lane = tid & 63;
  const int cg   = lane & 1;
  const int kc   = lane >> 1;        // 32 K-chunks per wave
  const int bg   = blockIdx.x / NHG; // batch group 0..7
  const int hg   = blockIdx.x % NHG; // hidden group 0..31

  // ---- W slice -> registers via volatile asm (non-rematerializable).
  // Lane owns 4 consecutive local cols x 24 k. Issue all 24 loads, then
  // one waitcnt (volatile asm blocks keep their mutual order).
  float4 Wr4[6][4];                  // [j][kk] -> 4 cols in .x..w
  const int clb  = wave * 8 + cg * 4;
  const int col0 = (clb >> 4) * HH + hg * 16 + (clb & 15);
  #pragma unroll
  for (int j = 0; j < 6; ++j)
    #pragma unroll
    for (int kk = 0; kk < 4; ++kk) {
      const int k = kc * 4 + 128 * j + kk;
      const float* wp = &W[(size_t)k * GG + col0];
      asm volatile("global_load_dwordx4 %0, %1, off"
                   : "=v"(Wr4[j][kk]) : "v"(wp));
    }
  asm volatile("s_waitcnt vmcnt(0)" ::: "memory");

  // Butterfly output mapping: lane ends with flat acc index afin
  // (bit-reversed kc) = output (wb, wcl).
  const int afin = (((lane >> 1) & 1) << 4) | (((lane >> 2) & 1) << 3) |
                   (((lane >> 3) & 1) << 2) | (((lane >> 4) & 1) << 1) |
                   ((lane >> 5) & 1);
  const int wb   = afin >> 2;
  const int wcl  = clb + (afin & 3);
  const float wbias = bias[(wcl >> 4) * HH + hg * 16 + (wcl & 15)];

  float c_state = 0.0f;              // persistent cell state (tid < 128)

  // x prefetch registers: x(t) for this thread's (bl, kb4) slot
  const int bl_x  = tid >> 6;
  const int kb4_x = (tid & 63) * 4;
  const float* xrow = &x[(size_t)(bg * BPG + bl_x) * TT * II + kb4_x];
  float4 xreg = *(const float4*)&xrow[0];            // x(0)

  for (int t = 0; t < TT; ++t) {
    // ---- A: write prefetched x(t) into LDS
    *(float4*)&xh[bl_x][kb4_x] = xreg;
    __syncthreads();                                  // B: x staged

    float acc[32];
    #pragma unroll
    for (int i = 0; i < 32; ++i) acc[i] = 0.0f;

    // ---- C: x-part of GEMM (j=0,1 -> k<256); overlaps writers' tail
    #pragma unroll
    for (int j = 0; j < 2; ++j) {
      const int kb = kc * 4 + 128 * j;
      const float4 w0 = Wr4[j][0], w1 = Wr4[j][1];
      const float4 w2 = Wr4[j][2], w3 = Wr4[j][3];
      #pragma unroll
      for (int bl = 0; bl < 8; ++bl) {
        const float4 xv = *(const float4*)&xh[bl][kb];
        acc[bl*4+0] = fmaf(xv.w, w3.x, fmaf(xv.z, w2.x,
                      fmaf(xv.y, w1.x, fmaf(xv.x, w0.x, acc[bl*4+0]))));
        acc[bl*4+1] = fmaf(xv.w, w3.y, fmaf(xv.z, w2.y,
                      fmaf(xv.y, w1.y, fmaf(xv.x, w0.y, acc[bl*4+1]))));
        acc[bl*4+2] = fmaf(xv.w, w3.z, fmaf(xv.z, w2.z,
                      fmaf(xv.y, w1.z, fmaf(xv.x, w0.z, acc[bl*4+2]))));
        acc[bl*4+3] = fmaf(xv.w, w3.w, fmaf(xv.z, w2.w,
                      fmaf(xv.y, w1.w, fmaf(xv.x, w0.w, acc[bl*4+3]))));
      }
    }

    // ---- D: wait for all 32 WGs of this group to publish h(t).
    // Explicit system-scope (sc0 sc1) polling load: bypasses L1/L2,
    // always observes the coherence point. No cache maintenance ops.
    if (t > 0 && tid == 0) {
      const unsigned tgt = (unsigned)t * NHG;
      const unsigned* bp = &bar[bg];
      unsigned v;
      for (;;) {
        asm volatile("global_load_dword %0, %1, off sc0 sc1\n\t"
                     "s_waitcnt vmcnt(0)"
                     : "=v"(v) : "v"(bp) : "memory");
        if (v >= tgt) break;
        asm volatile("s_sleep 2" ::: "memory");
      }
    }
    __syncthreads();                                  // E: h(t) published

    // ---- F: stage h(t): 512 threads x 2 float4, sc0 sc1 bypass loads
    if (t == 0) {
      const int bl0 = tid >> 7, k4 = (tid & 127) * 4;
      const float4 z = {0.f, 0.f, 0.f, 0.f};
      *(float4*)&xh[bl0][II + k4]     = z;
      *(float4*)&xh[bl0 + 4][II + k4] = z;
    } else {
      const float* hb = hbuf + (size_t)(t & 1) * BB * HH;
      const int bl0 = tid >> 7, k4 = (tid & 127) * 4;
      const float* p0 = &hb[(size_t)(bg * BPG + bl0) * HH + k4];
      const float* p1 = &hb[(size_t)(bg * BPG + bl0 + 4) * HH + k4];
      float4 h0, h1;
      asm volatile("global_load_dwordx4 %0, %2, off sc0 sc1\n\t"
                   "global_load_dwordx4 %1, %3, off sc0 sc1\n\t"
                   "s_waitcnt vmcnt(0)"
                   : "=&v"(h0), "=&v"(h1)
                   : "v"(p0), "v"(p1) : "memory");
      *(float4*)&xh[bl0][II + k4]     = h0;
      *(float4*)&xh[bl0 + 4][II + k4] = h1;
    }
    // prefetch x(t+1) (plain cached load; latency hides under h-GEMM)
    {
      const int tn = (t + 1 < TT) ? (t + 1) : (TT - 1);
      xreg = *(const float4*)&xrow[(size_t)tn * II];
    }
    __syncthreads();                                  // G: h staged

    // ---- H: h-part of GEMM (j=2..5)
    #pragma unroll
    for (int j = 2; j < 6; ++j) {
      const int kb = kc * 4 + 128 * j;
      const float4 w0 = Wr4[j][0], w1 = Wr4[j][1];
      const float4 w2 = Wr4[j][2], w3 = Wr4[j][3];
      #pragma unroll
      for (int bl = 0; bl < 8; ++bl) {
        const float4 xv = *(const float4*)&xh[bl][kb];
        acc[bl*4+0] = fmaf(xv.w, w3.x, fmaf(xv.z, w2.x,
                      fmaf(xv.y, w1.x, fmaf(xv.x, w0.x, acc[bl*4+0]))));
        acc[bl*4+1] = fmaf(xv.w, w3.y, fmaf(xv.z, w2.y,
                      fmaf(xv.y, w1.y, fmaf(xv.x, w0.y, acc[bl*4+1]))));
        acc[bl*4+2] = fmaf(xv.w, w3.z, fmaf(xv.z, w2.z,
                      fmaf(xv.y, w1.z, fmaf(xv.x, w0.z, acc[bl*4+2]))));
        acc[bl*4+3] = fmaf(xv.w, w3.w, fmaf(xv.z, w2.w,
                      fmaf(xv.y, w1.w, fmaf(xv.x, w0.w, acc[bl*4+3]))));
      }
    }

    // ---- I: halving butterfly over the 32 kc-lanes
    #pragma unroll
    for (int s = 0; s < 5; ++s) {
      const int m   = 2 << s;
      const int cnt = 16 >> s;
      const bool hi = (lane & m) != 0;
      #pragma unroll
      for (int i = 0; i < cnt; ++i) {
        const float send  = hi ? acc[i] : acc[i + cnt];
        const float other = __shfl_xor(send, m, 64);
        acc[i] = (hi ? acc[i + cnt] : acc[i]) + other;
      }
    }
    gates[wb][wcl] = acc[0] + wbias;
    __syncthreads();                                  // J: gates ready

    // ---- K: elementwise update; h published via sc0 sc1 write-through
    if (tid < 128) {
      const int ubt = tid >> 4, uh = tid & 15;
      const float gi = gates[ubt][uh];
      const float gj = gates[ubt][16 + uh];
      const float gf = gates[ubt][32 + uh];
      const float go = gates[ubt][48 + uh];
      c_state = fsig(gf + 1.0f) * c_state + fsig(gi) * ftanh(gj);
      const float hn = fsig(go) * ftanh(c_state);
      const int gb = bg * BPG + ubt;
      const int gh = hg * 16 + uh;
      out[((size_t)gb * TT + t) * HH + gh] = hn;      // plain store
      float* hp = &hbuf[(size_t)((t + 1) & 1) * BB * HH
                        + (size_t)gb * HH + gh];
      asm volatile("global_store_dword %0, %1, off sc0 sc1"
                   :: "v"(hp), "v"(hn) : "memory");
    }
    // L: drain every wave's stores to the coherence point, then barrier
    asm volatile("s_waitcnt vmcnt(0)" ::: "memory");
    __syncthreads();

    // ---- M: arrival — relaxed RMW, executes at the coherence point
    if (tid == 0) {
      __hip_atomic_fetch_add(&bar[bg], 1u, __ATOMIC_RELAXED,
                             __HIP_MEMORY_SCOPE_SYSTEM);
    }
  }
}

extern "C" void kernel_launch(void* const* d_in, const int* in_sizes, int n_in,
                              void* d_out, int out_size, void* d_ws, size_t ws_size,
                              hipStream_t stream) {
  const float* x    = (const float*)d_in[0];   // [64,1024,256]
  const float* W    = (const float*)d_in[1];   // [768,2048]
  const float* bias = (const float*)d_in[2];   // [2048]
  float* out = (float*)d_out;                  // [64,1024,512]

  unsigned int* bar = (unsigned int*)d_ws;           // 8 counters
  float* hbuf = (float*)((char*)d_ws + 256);         // 2 x [64,512] f32

  zero_bar_kernel<<<1, 64, 0, stream>>>(bar);
  lstm_persistent<<<NWG, NTHR, PAD_LDS_BYTES, stream>>>(x, W, bias, out,
                                                        hbuf, bar);
}